// Round 2
// baseline (46176.456 us; speedup 1.0000x reference)
//
#include <hip/hip_runtime.h>

#define NN 8192
#define DD 32
// stagger-padded LDS index: +4 floats of pad per 16 (keeps 16B alignment)
#define SIDX(c) ((c) + 4 * ((c) >> 4))

constexpr float kEps   = 0.1f;
constexpr float kStab  = 1e-8f;
constexpr float kMass  = 1.0f / 8192.0f;     // mu = nu = 1/n
constexpr float kInvSc = 1.0f / 256.0f;      // K stored as fp8 of 256*K
constexpr float kLnSc  = 5.545177444479562f; // ln(256)

typedef float v2f __attribute__((ext_vector_type(2)));

__device__ inline void cvt8x4(unsigned int w, float* out) {
    v2f lo = __builtin_amdgcn_cvt_pk_f32_fp8(w, false);
    v2f hi = __builtin_amdgcn_cvt_pk_f32_fp8(w, true);
    out[0] = lo.x; out[1] = lo.y; out[2] = hi.x; out[3] = hi.y;
}
__device__ inline void cvt16(uint4 kk, float* f) {
    cvt8x4(kk.x, f); cvt8x4(kk.y, f + 4); cvt8x4(kk.z, f + 8); cvt8x4(kk.w, f + 12);
}
__device__ inline unsigned int pack8x4(float a, float b, float c, float d) {
    int v = 0;
    v = __builtin_amdgcn_cvt_pk_fp8_f32(a, b, v, false);
    v = __builtin_amdgcn_cvt_pk_fp8_f32(c, d, v, true);
    return (unsigned int)v;
}
// dot of 16 fp8 values against 4 float4 v-registers
__device__ inline float dot16(uint4 kk, const float4* v4, float a) {
    float f[16];
    cvt16(kk, f);
    a = fmaf(f[0],  v4[0].x, a); a = fmaf(f[1],  v4[0].y, a);
    a = fmaf(f[2],  v4[0].z, a); a = fmaf(f[3],  v4[0].w, a);
    a = fmaf(f[4],  v4[1].x, a); a = fmaf(f[5],  v4[1].y, a);
    a = fmaf(f[6],  v4[1].z, a); a = fmaf(f[7],  v4[1].w, a);
    a = fmaf(f[8],  v4[2].x, a); a = fmaf(f[9],  v4[2].y, a);
    a = fmaf(f[10], v4[2].z, a); a = fmaf(f[11], v4[2].w, a);
    a = fmaf(f[12], v4[3].x, a); a = fmaf(f[13], v4[3].y, a);
    a = fmaf(f[14], v4[3].z, a); a = fmaf(f[15], v4[3].w, a);
    return a;
}
// c[j] += f8[j] * ur for 16 values
__device__ inline void axpy16(uint4 kk, float ur, float* c) {
    float f[16];
    cvt16(kk, f);
#pragma unroll
    for (int j = 0; j < 16; j++) c[j] = fmaf(f[j], ur, c[j]);
}

// ---------------------------------------------------------------- init u = 1
__global__ void sk_init_u(float* __restrict__ u) {
    u[blockIdx.x * 256 + threadIdx.x] = 1.0f;
}

// -------------------------------- build K8 = fp8(256*exp(-cost/eps)) for one pair
__global__ __launch_bounds__(256) void sk_build_k(const float* __restrict__ X,
                                                  const float* __restrict__ Y,
                                                  unsigned char* __restrict__ K) {
    __shared__ float xs[DD * 64];
    __shared__ float ys[DD * 64];
    __shared__ float sx[64], sy[64];
    const int t  = threadIdx.x;
    const int r0 = blockIdx.y * 64, c0 = blockIdx.x * 64;

    for (int idx = t; idx < DD * 64; idx += 256) {
        int d = idx >> 6, row = idx & 63;
        xs[idx] = X[(size_t)(r0 + row) * DD + d];
        ys[idx] = Y[(size_t)(c0 + row) * DD + d];
    }
    __syncthreads();
    if (t < 64) {
        float s = 0.f;
        for (int d = 0; d < DD; d++) { float v = xs[d * 64 + t]; s = fmaf(v, v, s); }
        sx[t] = s;
    } else if (t < 128) {
        int q = t - 64; float s = 0.f;
        for (int d = 0; d < DD; d++) { float v = ys[d * 64 + q]; s = fmaf(v, v, s); }
        sy[q] = s;
    }
    __syncthreads();

    const int tr = t >> 4, tc = t & 15;
    float acc[4][4] = {};
    for (int d = 0; d < DD; d++) {
        const float4 xa = *reinterpret_cast<const float4*>(&xs[d * 64 + 4 * tr]);
        const float4 yb = *reinterpret_cast<const float4*>(&ys[d * 64 + 4 * tc]);
        const float xav[4] = {xa.x, xa.y, xa.z, xa.w};
        const float ybv[4] = {yb.x, yb.y, yb.z, yb.w};
#pragma unroll
        for (int a = 0; a < 4; a++)
#pragma unroll
            for (int b = 0; b < 4; b++) acc[a][b] = fmaf(xav[a], ybv[b], acc[a][b]);
    }
#pragma unroll
    for (int a = 0; a < 4; a++) {
        const int r = r0 + 4 * tr + a;
        const float sxa = sx[4 * tr + a];
        float e[4];
#pragma unroll
        for (int b = 0; b < 4; b++) {
            float cost = sxa + sy[4 * tc + b] - 2.0f * acc[a][b];
            cost = fmaxf(cost, 0.0f);
            e[b] = expf(fmaf(-10.0f, cost, kLnSc));   // 256 * exp(-cost/eps)
        }
        *reinterpret_cast<unsigned int*>(&K[(size_t)r * NN + c0 + 4 * tc]) =
            pack8x4(e[0], e[1], e[2], e[3]);
    }
}

// -------------------------------- initial column sums: rc[z] += K[z]^T u[z] (u = 1)
__global__ __launch_bounds__(256) void sk_colsum(const unsigned char* __restrict__ K8,
                                                 const float* __restrict__ u,
                                                 float* __restrict__ rc_out) {
    __shared__ float us[128];
    __shared__ float red[4 * 1280];   // 4 waves x staggered 1024
    const int t = threadIdx.x, lane = t & 63, w = t >> 6;
    const int z = blockIdx.z;
    const int c0 = blockIdx.x * 1024, r0 = blockIdx.y * 128;
    const unsigned char* K = K8 + (size_t)z * NN * NN;
    if (t < 128) us[t] = u[z * NN + r0 + t];
    __syncthreads();

    float acc[16] = {};
    const unsigned char* p = K + (size_t)(r0 + 32 * w) * NN + c0 + 16 * lane;
    for (int i = 0; i < 32; i += 4) {
        uint4 k0 = *reinterpret_cast<const uint4*>(p);
        uint4 k1 = *reinterpret_cast<const uint4*>(p + (size_t)NN);
        uint4 k2 = *reinterpret_cast<const uint4*>(p + (size_t)2 * NN);
        uint4 k3 = *reinterpret_cast<const uint4*>(p + (size_t)3 * NN);
        p += (size_t)4 * NN;
        const float u0 = us[32 * w + i + 0], u1 = us[32 * w + i + 1];
        const float u2 = us[32 * w + i + 2], u3 = us[32 * w + i + 3];
        float f[16];
        cvt16(k0, f);
#pragma unroll
        for (int j = 0; j < 16; j++) acc[j] = fmaf(f[j], u0, acc[j]);
        cvt16(k1, f);
#pragma unroll
        for (int j = 0; j < 16; j++) acc[j] = fmaf(f[j], u1, acc[j]);
        cvt16(k2, f);
#pragma unroll
        for (int j = 0; j < 16; j++) acc[j] = fmaf(f[j], u2, acc[j]);
        cvt16(k3, f);
#pragma unroll
        for (int j = 0; j < 16; j++) acc[j] = fmaf(f[j], u3, acc[j]);
    }
    float* rw = &red[w * 1280 + 20 * lane];   // SIDX(16*lane) = 20*lane
#pragma unroll
    for (int g = 0; g < 4; g++) {
        float4 v = {acc[4 * g + 0], acc[4 * g + 1], acc[4 * g + 2], acc[4 * g + 3]};
        *reinterpret_cast<float4*>(rw + 4 * g) = v;
    }
    __syncthreads();
    for (int c = t; c < 1024; c += 256) {
        const int sc = SIDX(c);
        const float s = red[sc] + red[1280 + sc] + red[2560 + sc] + red[3840 + sc];
        atomicAdd(&rc_out[z * NN + c0 + c], s);
    }
}

// -------------------------------- fused iteration, register-resident K panels:
// Block owns 32 rows x 8192 cols. Wave w owns col strip [2048w, 2048w+2048);
// lane owns 32 fixed cols (16 at c0+16*lane, 16 at c0+1024+16*lane) for ALL rows.
// v for those cols lives in registers. Per 8-row group: packed fp8 K held in 64
// VGPRs, used for row-sums (-> u_new via cross-wave LDS reduce) then re-converted
// in-register for column partial sums. K is read from HBM exactly once per iter.
__global__ __launch_bounds__(256, 3) void sk_iter(const unsigned char* __restrict__ K8,
                                                  const float* __restrict__ rc_in,
                                                  float* __restrict__ rc_next,
                                                  float* __restrict__ rc_zero,
                                                  float* __restrict__ u_out,
                                                  int last) {
    __shared__ float cs[10240];        // staggered 8192: colsum drain buffer
    __shared__ float red[4][4][8];     // group x wave x row partial rowsums
    const int t = threadIdx.x, lane = t & 63, w = t >> 6;
    const int z = blockIdx.z;
    const unsigned char* K = K8 + (size_t)z * NN * NN;
    const int rowbase = blockIdx.x * 32;
    const int c0 = 2048 * w;

    // zero the buffer iteration t+1 accumulates into (triple-buffer race-free)
    if (!last && t < 32) rc_zero[(size_t)z * NN + rowbase + t] = 0.0f;

    // ---- v for this lane's 32 columns, in registers
    float4 vv[8];
    {
        const float* rcz = rc_in + (size_t)z * NN + c0 + 16 * lane;
#pragma unroll
        for (int i = 0; i < 4; i++) vv[i] = reinterpret_cast<const float4*>(rcz)[i];
#pragma unroll
        for (int i = 0; i < 4; i++) vv[4 + i] = reinterpret_cast<const float4*>(rcz + 1024)[i];
#pragma unroll
        for (int i = 0; i < 8; i++) {
            vv[i].x = kMass * __builtin_amdgcn_rcpf(fmaf(vv[i].x, kInvSc, kStab));
            vv[i].y = kMass * __builtin_amdgcn_rcpf(fmaf(vv[i].y, kInvSc, kStab));
            vv[i].z = kMass * __builtin_amdgcn_rcpf(fmaf(vv[i].z, kInvSc, kStab));
            vv[i].w = kMass * __builtin_amdgcn_rcpf(fmaf(vv[i].w, kInvSc, kStab));
        }
    }

    float cacc[32] = {};
#pragma unroll
    for (int g = 0; g < 4; g++) {
        const int rb = rowbase + 8 * g;
        // load 8 rows of packed fp8 (this lane's 32 cols) into registers
        uint4 kr0[8], kr1[8];
        {
            const unsigned char* kp = K + (size_t)rb * NN + c0 + 16 * lane;
#pragma unroll
            for (int r = 0; r < 8; r++) {
                kr0[r] = *reinterpret_cast<const uint4*>(kp);
                kr1[r] = *reinterpret_cast<const uint4*>(kp + 1024);
                kp += NN;
            }
        }
        // phase 1: per-lane partial row sums -> wave reduce -> LDS
#pragma unroll
        for (int r = 0; r < 8; r++) {
            float p = dot16(kr0[r], &vv[0], 0.0f);
            p = dot16(kr1[r], &vv[4], p);
            for (int off = 32; off > 0; off >>= 1) p += __shfl_down(p, off);
            if (lane == 0) red[g][w][r] = p;
        }
        __syncthreads();
        // every wave computes u for the 8 rows (identical fp math, no 2nd sync)
        float ug[8];
#pragma unroll
        for (int r = 0; r < 8; r++) {
            const float s = red[g][0][r] + red[g][1][r] + red[g][2][r] + red[g][3][r];
            ug[r] = kMass / (s * kInvSc + kStab);
            if (w == 0 && lane == r) u_out[(size_t)z * NN + rb + r] = ug[r];
        }
        // phase 2: re-convert the SAME registers, accumulate column partials
#pragma unroll
        for (int r = 0; r < 8; r++) {
            axpy16(kr0[r], ug[r], &cacc[0]);
            axpy16(kr1[r], ug[r], &cacc[16]);
        }
    }
    if (last) return;   // uniform: final iteration needs no next colsum

    // ---- drain: stage strip partials in LDS, then rotated coalesced atomics
    {
        float* b0 = &cs[SIDX(c0 + 16 * lane)];          // base%16==0 -> SIDX(+j)=SIDX+j
        float* b1 = &cs[SIDX(c0 + 1024 + 16 * lane)];
#pragma unroll
        for (int q = 0; q < 4; q++) {
            float4 v4 = {cacc[4 * q + 0], cacc[4 * q + 1], cacc[4 * q + 2], cacc[4 * q + 3]};
            *reinterpret_cast<float4*>(b0 + 4 * q) = v4;
        }
#pragma unroll
        for (int q = 0; q < 4; q++) {
            float4 v4 = {cacc[16 + 4 * q + 0], cacc[16 + 4 * q + 1],
                         cacc[16 + 4 * q + 2], cacc[16 + 4 * q + 3]};
            *reinterpret_cast<float4*>(b1 + 4 * q) = v4;
        }
    }
    __syncthreads();
    float* rcn = rc_next + (size_t)z * NN;
    const int rot = (blockIdx.x * 32) & (NN - 1);   // decorrelate atomic order per block
    for (int i = t; i < NN; i += 256) {
        const int c = (i + rot) & (NN - 1);
        atomicAdd(&rcn[c], cs[SIDX(c)]);
    }
}

// -------------------------------- w[z] = sum u_i K_ij v_j cost_ij, cost = -eps*ln(K)
__global__ __launch_bounds__(256) void sk_wsum(const unsigned char* __restrict__ K8,
                                               const float* __restrict__ rc_in,
                                               const float* __restrict__ u,
                                               double* __restrict__ acc_out) {
    __shared__ float vs[10240];
    __shared__ double wred[4];
    const int t = threadIdx.x;
    const int z = blockIdx.z;
    const unsigned char* K = K8 + (size_t)z * NN * NN;
    const float* rc = rc_in + z * NN;
#pragma unroll
    for (int q = 0; q < 8; q++) {
        const int j = 4 * t + 1024 * q;
        float4 r = *reinterpret_cast<const float4*>(rc + j);
        float4 g;
        g.x = kMass * __builtin_amdgcn_rcpf(fmaf(r.x, kInvSc, kStab));
        g.y = kMass * __builtin_amdgcn_rcpf(fmaf(r.y, kInvSc, kStab));
        g.z = kMass * __builtin_amdgcn_rcpf(fmaf(r.z, kInvSc, kStab));
        g.w = kMass * __builtin_amdgcn_rcpf(fmaf(r.w, kInvSc, kStab));
        *reinterpret_cast<float4*>(&vs[SIDX(j)]) = g;
    }
    __syncthreads();

    const int lane = t & 63, w = t >> 6;
    const int rbase = blockIdx.x * 32 + 8 * w;
    float pr[8] = {};
    const unsigned char* rp = K + (size_t)rbase * NN + 16 * lane;
    for (int s = 0; s < 8; s++) {
        const float* vp = &vs[20 * lane + 1280 * s];
        float vv[16];
#pragma unroll
        for (int g = 0; g < 4; g++) {
            float4 v4 = *reinterpret_cast<const float4*>(vp + 4 * g);
            vv[4 * g] = v4.x; vv[4 * g + 1] = v4.y; vv[4 * g + 2] = v4.z; vv[4 * g + 3] = v4.w;
        }
        const unsigned char* ps = rp + 1024 * s;
#pragma unroll
        for (int r = 0; r < 8; r++) {
            uint4 kk = *reinterpret_cast<const uint4*>(ps + (size_t)r * NN);
            float f[16];
            cvt16(kk, f);
            float a = pr[r];
#pragma unroll
            for (int j = 0; j < 16; j++) {
                // term k*v*ln(k): zero when f==0 since f*v==0
                a = fmaf(f[j] * vv[j], __logf(fmaxf(f[j], 1e-30f) * kInvSc), a);
            }
            pr[r] = a;
        }
    }
    double lacc = 0.0;
#pragma unroll
    for (int r = 0; r < 8; r++)
        lacc += (double)(u[z * NN + rbase + r] * pr[r]);
    lacc *= (double)kInvSc;
    for (int off = 32; off > 0; off >>= 1) lacc += __shfl_down(lacc, off);
    if (lane == 0) wred[w] = lacc;
    __syncthreads();
    if (t == 0) {
        double total = -(double)kEps * (wred[0] + wred[1] + wred[2] + wred[3]);
        atomicAdd(&acc_out[z], total);
    }
}

// ------------------------------------------------- combine
__global__ void sk_combine(const double* __restrict__ acc, float* __restrict__ out) {
    if (threadIdx.x == 0)
        out[0] = (float)((acc[0] - 0.5 * acc[1] - 0.5 * acc[2]) / 8192.0);
}

extern "C" void kernel_launch(void* const* d_in, const int* in_sizes, int n_in,
                              void* d_out, int out_size, void* d_ws, size_t ws_size,
                              hipStream_t stream) {
    const float* src = (const float*)d_in[0];
    const float* tgt = (const float*)d_in[1];
    float* out = (float*)d_out;
    char* ws = (char*)d_ws;

    const size_t need3 = 3ull * NN * NN + 16ull * NN * sizeof(float) + 1024;
    const bool batched = ws_size >= need3;
    const int B = batched ? 3 : 1;

    const size_t koff = (size_t)B * NN * NN;
    unsigned char* K8 = (unsigned char*)ws;
    float*  u    = (float*)(ws + koff);
    float*  rc0  = u + (size_t)B * NN;
    float*  rc1  = rc0 + (size_t)B * NN;
    float*  rc2  = rc1 + (size_t)B * NN;
    double* wacc = (double*)(rc2 + (size_t)B * NN);
    float* rc[3] = {rc0, rc1, rc2};

    hipMemsetAsync(wacc, 0, 3 * sizeof(double), stream);
    const float* pts[3][2] = {{src, tgt}, {src, src}, {tgt, tgt}};

    if (batched) {
        // rc0 (initial colsum target) and rc1 (iter-1 target) must start zeroed;
        // rc2 is zeroed by iter 1.
        hipMemsetAsync(rc0, 0, 2ull * 3 * NN * sizeof(float), stream);
        sk_init_u<<<3 * NN / 256, 256, 0, stream>>>(u);
        for (int i = 0; i < 3; i++)
            sk_build_k<<<dim3(128, 128, 1), 256, 0, stream>>>(pts[i][0], pts[i][1],
                                                              K8 + (size_t)i * NN * NN);
        sk_colsum<<<dim3(8, 64, 3), 256, 0, stream>>>(K8, u, rc0);   // rc_1
        // iter t: reads rc[(t-1)%3] (=rc_t), accumulates rc[t%3] (=rc_{t+1},
        // pre-zeroed), zeroes rc[(t+1)%3] (read-complete since iter t-1).
        for (int t = 1; t <= 100; t++)
            sk_iter<<<dim3(256, 1, 3), 256, 0, stream>>>(K8, rc[(t - 1) % 3], rc[t % 3],
                                                         rc[(t + 1) % 3], u, t == 100 ? 1 : 0);
        // after t=100: u = u_final, rc0 = rc_100 (makes v_100)
        sk_wsum<<<dim3(256, 1, 3), 256, 0, stream>>>(K8, rc0, u, wacc);
    } else {
        for (int tf = 0; tf < 3; tf++) {
            hipMemsetAsync(rc0, 0, 2ull * NN * sizeof(float), stream);
            sk_init_u<<<NN / 256, 256, 0, stream>>>(u);
            sk_build_k<<<dim3(128, 128, 1), 256, 0, stream>>>(pts[tf][0], pts[tf][1], K8);
            sk_colsum<<<dim3(8, 64, 1), 256, 0, stream>>>(K8, u, rc0);
            for (int t = 1; t <= 100; t++)
                sk_iter<<<dim3(256, 1, 1), 256, 0, stream>>>(K8, rc[(t - 1) % 3], rc[t % 3],
                                                             rc[(t + 1) % 3], u, t == 100 ? 1 : 0);
            sk_wsum<<<dim3(256, 1, 1), 256, 0, stream>>>(K8, rc0, u, &wacc[tf]);
        }
    }
    sk_combine<<<1, 64, 0, stream>>>(wacc, out);
}